// Round 17
// baseline (361.362 us; speedup 1.0000x reference)
//
#include <hip/hip_runtime.h>

typedef __bf16 bf16x8 __attribute__((ext_vector_type(8)));
typedef __bf16 bf16x4 __attribute__((ext_vector_type(4)));
typedef float f32x4 __attribute__((ext_vector_type(4)));

__device__ __forceinline__ float bf2f(unsigned short u) {
  union { unsigned int i; float f; } v; v.i = ((unsigned int)u) << 16; return v.f;
}
__device__ __forceinline__ unsigned short f2bf(float f) {
  union { float f; unsigned int i; } v; v.f = f;
  unsigned int u = v.i;
  u += 0x7fffu + ((u >> 16) & 1u);
  return (unsigned short)(u >> 16);
}

#define SB()  __builtin_amdgcn_sched_barrier(0)
#define BAR() __builtin_amdgcn_s_barrier()

// ---------------- fused convert: x (dual), flat weights, transposed who/wvo
__global__ void cvt_all(const float* __restrict__ x,
                        const float* __restrict__ wv, const float* __restrict__ wh,
                        const float* __restrict__ w1, const float* __restrict__ w2,
                        const float* __restrict__ who, const float* __restrict__ wvo,
                        unsigned short* __restrict__ xb, unsigned short* __restrict__ xt,
                        unsigned short* __restrict__ wvb, unsigned short* __restrict__ whb,
                        unsigned short* __restrict__ w1b, unsigned short* __restrict__ w2b,
                        unsigned short* __restrict__ whoT, unsigned short* __restrict__ wvoT)
{
  const int bid = blockIdx.x;
  const int t = threadIdx.x;
  if (bid < 18432) {
    const int ro = bid * 2 + (t >> 7);           // xt row = s*192+b
    const int idx = t & 127;
    const int s = ro / 192, b = ro - s * 192;
    const int ri = b * 192 + s;                  // x/xb row
    float4 v = *(const float4*)&x[(size_t)ri * 512 + idx * 4];
    ushort4 o;
    o.x = f2bf(v.x); o.y = f2bf(v.y); o.z = f2bf(v.z); o.w = f2bf(v.w);
    *(ushort4*)&xb[(size_t)ri * 512 + idx * 4] = o;
    *(ushort4*)&xt[(size_t)ro * 512 + idx * 4] = o;
  } else if (bid < 20736) {
    int q = (bid - 18432) * 256 + t;
    const float* src; unsigned short* dst;
    if (q < 196608)      { src = wv;  dst = wvb; }
    else if (q < 393216) { src = wh;  dst = whb; q -= 196608; }
    else if (q < 524288) { src = w1;  dst = w1b; q -= 393216; }
    else                 { src = w2;  dst = w2b; q -= 524288; }
    float4 v = ((const float4*)src)[q];
    ushort4 o;
    o.x = f2bf(v.x); o.y = f2bf(v.y); o.z = f2bf(v.z); o.w = f2bf(v.w);
    ((ushort4*)dst)[q] = o;
  } else {
    const int tb = bid - 20736;
    const float* src = (tb < 256) ? who : wvo;
    unsigned short* dst = (tb < 256) ? whoT : wvoT;
    const int j = (tb & 255) * 2 + (t >> 7);
    const int i0 = (t & 127) * 4;
    ushort4 o;
    o.x = f2bf(src[(size_t)(i0 + 0) * 512 + j]);
    o.y = f2bf(src[(size_t)(i0 + 1) * 512 + j]);
    o.z = f2bf(src[(size_t)(i0 + 2) * 512 + j]);
    o.w = f2bf(src[(size_t)(i0 + 3) * 512 + j]);
    *(ushort4*)&dst[(size_t)j * 512 + i0] = o;
  }
}

// ---------------- async global->LDS 16B ----------------
__device__ __forceinline__ void async16(const void* g, void* s) {
  __builtin_amdgcn_global_load_lds(
      (const __attribute__((address_space(1))) unsigned int*)g,
      (__attribute__((address_space(3))) unsigned int*)s, 16, 0, 0);
}

// ---------------- fuse_bias device body: bf = b1 + W1a.hob + W1b.vob ------
__device__ __forceinline__ void fuse_bias_core(int bid,
    const float* b1, const float* hob, const float* vob,
    const float* w1, float* bf)
{
  const int gid = bid * 256 + (int)threadIdx.x;
  const int o = gid >> 4, g = gid & 15;
  if (o < 512) {
    const float* row = w1 + (size_t)o * 1024;
    float s = 0.f;
    #pragma unroll 8
    for (int m = g * 32; m < g * 32 + 32; ++m) s += row[m] * hob[m];
    #pragma unroll 8
    for (int m = g * 32; m < g * 32 + 32; ++m) s += row[512 + m] * vob[m];
    s += __shfl_xor(s, 1);
    s += __shfl_xor(s, 2);
    s += __shfl_xor(s, 4);
    s += __shfl_xor(s, 8);
    if (g == 0) bf[o] = s + b1[o];
  }
}

// ======== 128x128 bf16 GEMM core (R12-proven; VT + G GEMMs) ===============
// BK=32, 4 waves (2x2), 3-slot pipeline, distance 2, counted vmcnt(4),
// single barrier per K-step. XCD+group-major L2 blocking; XOR-swizzle LDS.
// BIASROW=1: bias indexed by output ROW.
template<int OUTF32, int RELU, int BIASROW, int ADDB>
__device__ __forceinline__ void gemm_core(int bid0, int nwg,
    unsigned short* As, unsigned short* Bs,
    const unsigned short* A, const unsigned short* Bt, void* Cv, const float* bias,
    int M, int N, int K, int lda, int ldb, int ldC, int colOff)
{
  const int per = nwg >> 3;
  const int lb = (bid0 & 7) * per + (bid0 >> 3);   // bijective, nwg%8==0
  const int nb = N >> 7;
  const int grp = lb / (4 * nb);
  const int r = lb - grp * 4 * nb;
  const int tm = grp * 4 + (r & 3);
  const int tn = r >> 2;

  const int t = threadIdx.x;
  const int w = t >> 6, l = t & 63;
  const int wr = w >> 1, wc = w & 1;
  const int lr = l & 15, kg = l >> 4;

  const unsigned short* Abase = A + (size_t)tm * 128 * lda;
  const unsigned short* Bbase = Bt + (size_t)tn * 128 * ldb;

  const int r0 = t >> 2;
  const int s0 = (((t & 3) ^ ((t >> 3) & 3))) * 8;
  const size_t ga0 = (size_t)r0 * lda + s0;
  const size_t ga1 = (size_t)(64 + r0) * lda + s0;
  const size_t gb0 = (size_t)r0 * ldb + s0;
  const size_t gb1 = (size_t)(64 + r0) * ldb + s0;
  const int ldsoff = w * 512;

  const f32x4 zero4 = {0.f, 0.f, 0.f, 0.f};
  f32x4 acc[4][4];
  #pragma unroll
  for (int m = 0; m < 4; ++m)
    #pragma unroll
    for (int n = 0; n < 4; ++n) acc[m][n] = zero4;

  auto stage = [&](int kt, int slot) {
    async16(Abase + ga0 + kt, &As[slot * 4096 + ldsoff]);
    async16(Abase + ga1 + kt, &As[slot * 4096 + 2048 + ldsoff]);
    async16(Bbase + gb0 + kt, &Bs[slot * 4096 + ldsoff]);
    async16(Bbase + gb1 + kt, &Bs[slot * 4096 + 2048 + ldsoff]);
  };

  const int nk = K >> 5;
  stage(0, 0);
  stage(32, 1);

  const int rsw = (kg ^ ((lr >> 1) & 3)) * 8;

  int cur = 0;
  for (int it = 0; it < nk; ++it) {
    if (it + 1 < nk) asm volatile("s_waitcnt vmcnt(4)" ::: "memory");
    else             asm volatile("s_waitcnt vmcnt(0)" ::: "memory");
    SB(); BAR(); SB();

    int st = cur + 2; if (st >= 3) st -= 3;
    if (it + 2 < nk) stage((it + 2) << 5, st);

    bf16x8 af[4], bfv[4];
    #pragma unroll
    for (int m = 0; m < 4; ++m)
      af[m] = *(const bf16x8*)&As[cur * 4096 + (wr * 64 + m * 16 + lr) * 32 + rsw];
    #pragma unroll
    for (int n = 0; n < 4; ++n)
      bfv[n] = *(const bf16x8*)&Bs[cur * 4096 + (wc * 64 + n * 16 + lr) * 32 + rsw];
    #pragma unroll
    for (int m = 0; m < 4; ++m)
      #pragma unroll
      for (int n = 0; n < 4; ++n)
        acc[m][n] = __builtin_amdgcn_mfma_f32_16x16x32_bf16(af[m], bfv[n],
                                                            acc[m][n], 0, 0, 0);
    cur = cur + 1; if (cur >= 3) cur = 0;
  }

  const int row0 = tm * 128 + wr * 64;
  const int colL0 = tn * 128 + wc * 64;

  #pragma unroll
  for (int n = 0; n < 4; ++n) {
    const int ccol = colL0 + n * 16 + lr;
    const float bvc = (ADDB && !BIASROW) ? bias[ccol] : 0.f;
    #pragma unroll
    for (int m = 0; m < 4; ++m) {
      #pragma unroll
      for (int r2 = 0; r2 < 4; ++r2) {
        const int crow = row0 + m * 16 + kg * 4 + r2;
        float v = acc[m][n][r2] + ((ADDB && BIASROW) ? bias[crow] : bvc);
        if (RELU) v = fmaxf(v, 0.f);
        if (OUTF32)
          ((float*)Cv)[(size_t)crow * ldC + colOff + ccol] = v;
        else
          ((unsigned short*)Cv)[(size_t)crow * ldC + colOff + ccol] = f2bf(v);
      }
    }
  }
}

// ======== 256x128 bf16 GEMM core (QK / MLP; M%256==0, tm-count%4==0) ======
// Same R12-proven schedule scaled: BK=32, 4 waves (2x2), per-wave 128x64
// (8x4 frags -> intensity 29 vs 22 FLOP/LDS-byte), 3-slot pipeline
// (A 16KB + B 8KB per slot = 72 KB -> 2 blocks/CU), distance 2, counted
// vmcnt(6) (6 loads/K-step), single barrier per K-step. Swizzle identities
// re-verified: f(row)=(row>>1)&3 invariant under +64 (stage rows) and
// +wr*128/+m*16 (read rows) => rsw unchanged. Register shape = R7's
// (acc[8][4], af[8], literal indices only — no spill there, rule-20 safe).
template<int OUTF32, int RELU, int ADDB>
__device__ __forceinline__ void gemm_core256(int bid0, int nwg,
    unsigned short* As, unsigned short* Bs,    // As: 3*8192, Bs: 3*4096 shorts
    const unsigned short* A, const unsigned short* Bt, void* Cv, const float* bias,
    int N, int K, int lda, int ldb, int ldC)
{
  const int per = nwg >> 3;
  const int lb = (bid0 & 7) * per + (bid0 >> 3);   // bijective, nwg%8==0
  const int nb = N >> 7;                           // 128-col tiles
  const int grp = lb / (4 * nb);
  const int r = lb - grp * 4 * nb;
  const int tm = grp * 4 + (r & 3);                // 256-row tiles
  const int tn = r >> 2;

  const int t = threadIdx.x;
  const int w = t >> 6, l = t & 63;
  const int wr = w >> 1, wc = w & 1;
  const int lr = l & 15, kg = l >> 4;

  const unsigned short* Abase = A + (size_t)tm * 256 * lda;
  const unsigned short* Bbase = Bt + (size_t)tn * 128 * ldb;

  const int r0 = t >> 2;
  const int s0 = (((t & 3) ^ ((t >> 3) & 3))) * 8;
  const size_t ga0 = (size_t)r0 * lda + s0;
  const size_t ga1 = (size_t)(64 + r0) * lda + s0;
  const size_t ga2 = (size_t)(128 + r0) * lda + s0;
  const size_t ga3 = (size_t)(192 + r0) * lda + s0;
  const size_t gb0 = (size_t)r0 * ldb + s0;
  const size_t gb1 = (size_t)(64 + r0) * ldb + s0;
  const int ldsoff = w * 512;

  const f32x4 zero4 = {0.f, 0.f, 0.f, 0.f};
  f32x4 acc[8][4];
  #pragma unroll
  for (int m = 0; m < 8; ++m)
    #pragma unroll
    for (int n = 0; n < 4; ++n) acc[m][n] = zero4;

  auto stage = [&](int kt, int slot) {
    async16(Abase + ga0 + kt, &As[slot * 8192 + ldsoff]);
    async16(Abase + ga1 + kt, &As[slot * 8192 + 2048 + ldsoff]);
    async16(Abase + ga2 + kt, &As[slot * 8192 + 4096 + ldsoff]);
    async16(Abase + ga3 + kt, &As[slot * 8192 + 6144 + ldsoff]);
    async16(Bbase + gb0 + kt, &Bs[slot * 4096 + ldsoff]);
    async16(Bbase + gb1 + kt, &Bs[slot * 4096 + 2048 + ldsoff]);
  };

  const int nk = K >> 5;
  stage(0, 0);
  stage(32, 1);

  const int rsw = (kg ^ ((lr >> 1) & 3)) * 8;

  int cur = 0;
  for (int it = 0; it < nk; ++it) {
    if (it + 1 < nk) asm volatile("s_waitcnt vmcnt(6)" ::: "memory");
    else             asm volatile("s_waitcnt vmcnt(0)" ::: "memory");
    SB(); BAR(); SB();

    int st = cur + 2; if (st >= 3) st -= 3;
    if (it + 2 < nk) stage((it + 2) << 5, st);

    bf16x8 af[8], bfv[4];
    #pragma unroll
    for (int m = 0; m < 8; ++m)
      af[m] = *(const bf16x8*)&As[cur * 8192 + (wr * 128 + m * 16 + lr) * 32 + rsw];
    #pragma unroll
    for (int n = 0; n < 4; ++n)
      bfv[n] = *(const bf16x8*)&Bs[cur * 4096 + (wc * 64 + n * 16 + lr) * 32 + rsw];
    #pragma unroll
    for (int m = 0; m < 8; ++m)
      #pragma unroll
      for (int n = 0; n < 4; ++n)
        acc[m][n] = __builtin_amdgcn_mfma_f32_16x16x32_bf16(af[m], bfv[n],
                                                            acc[m][n], 0, 0, 0);
    cur = cur + 1; if (cur >= 3) cur = 0;
  }

  const int row0 = tm * 256 + wr * 128;
  const int colL0 = tn * 128 + wc * 64;

  #pragma unroll
  for (int n = 0; n < 4; ++n) {
    const int ccol = colL0 + n * 16 + lr;
    const float bvc = ADDB ? bias[ccol] : 0.f;
    #pragma unroll
    for (int m = 0; m < 8; ++m) {
      #pragma unroll
      for (int r2 = 0; r2 < 4; ++r2) {
        const int crow = row0 + m * 16 + kg * 4 + r2;
        float v = acc[m][n][r2] + bvc;
        if (RELU) v = fmaxf(v, 0.f);
        if (OUTF32)
          ((float*)Cv)[(size_t)crow * ldC + ccol] = v;
        else
          ((unsigned short*)Cv)[(size_t)crow * ldC + ccol] = f2bf(v);
      }
    }
  }
}

// ---------------- standalone GEMM kernel (MLP1 / MLP2; 256x128 core) ------
template<int OUTF32, int RELU, int ADDB>
__global__ __launch_bounds__(256, 2)
void gemm256_bt(const unsigned short* __restrict__ A,
                const unsigned short* __restrict__ Bt,
                void* __restrict__ Cv, const float* __restrict__ bias,
                int N, int K, int lda, int ldb, int ldC)
{
  __shared__ unsigned short smem[36864];           // 72 KB
  gemm_core256<OUTF32, RELU, ADDB>((int)blockIdx.x, (int)gridDim.x,
                                   smem, smem + 24576,
                                   A, Bt, Cv, bias, N, K, lda, ldb, ldC);
}

// ---------------- merged h-branch projection dispatch ---------------------
// [0,1152): VT-h 128^2 core  C=vt[512][36864] = Wv_h . xt^T  (bias by row)
// [1152,2304): QK-h 256x128 core (36864x1024)
// [2304,2320): G1; [2320,2336): G2; [2336,2368): fused bias (32 blocks).
// Section offsets multiples of 8 (XCD id preserved per section).
__global__ __launch_bounds__(256, 2)
void proj_h(const unsigned short* __restrict__ xb, const unsigned short* __restrict__ xt,
            const unsigned short* __restrict__ whb,
            const unsigned short* __restrict__ w1b,
            const unsigned short* __restrict__ whoT, const unsigned short* __restrict__ wvoT,
            unsigned short* __restrict__ vto, unsigned short* __restrict__ qko,
            unsigned short* __restrict__ G, float* __restrict__ bfz,
            const float* __restrict__ h_in_b,
            const float* __restrict__ b1, const float* __restrict__ hob,
            const float* __restrict__ vob, const float* __restrict__ w1f)
{
  __shared__ unsigned short smem[36864];
  const int bid = (int)blockIdx.x;
  if (bid < 1152)
    gemm_core<0,0,1,1>(bid, 1152, smem, smem + 12288, whb + 1024 * 512, xt, vto,
                       h_in_b + 1024, 512, 36864, 512, 512, 512, 36864, 0);
  else if (bid < 2304)
    gemm_core256<0,0,1>(bid - 1152, 1152, smem, smem + 24576, xb, whb, qko,
                        h_in_b, 1024, 512, 512, 512, 1024);
  else if (bid < 2320)
    gemm_core<0,0,0,0>(bid - 2304, 16, smem, smem + 12288, w1b, whoT, G,
                       bfz, 512, 512, 512, 1024, 512, 1024, 0);
  else if (bid < 2336)
    gemm_core<0,0,0,0>(bid - 2320, 16, smem, smem + 12288, w1b + 512, wvoT, G,
                       bfz, 512, 512, 512, 1024, 512, 1024, 512);
  else
    fuse_bias_core(bid - 2336, b1, hob, vob, w1f, bfz);
}

// ---------------- merged v-branch projection dispatch ---------------------
// [0,1152): VT-v 128^2 core; [1152,2304): QK-v 256x128 core
__global__ __launch_bounds__(256, 2)
void proj_v(const unsigned short* __restrict__ xb,
            const unsigned short* __restrict__ wvb,
            unsigned short* __restrict__ vto, unsigned short* __restrict__ qko,
            const float* __restrict__ v_in_b)
{
  __shared__ unsigned short smem[36864];
  const int bid = (int)blockIdx.x;
  if (bid < 1152)
    gemm_core<0,0,1,1>(bid, 1152, smem, smem + 12288, wvb + 1024 * 512, xb, vto,
                       v_in_b + 1024, 512, 36864, 512, 512, 512, 36864, 0);
  else
    gemm_core256<0,0,1>(bid - 1152, 1152, smem, smem + 24576, xb, wvb, qko,
                        v_in_b, 1024, 512, 512, 512, 1024);
}

// ---------------- MFMA sliding-window attention ---------------------------
// Block = (b, n, head-group of 4). Wave w handles head hg*4+w independently.
// qk: (36864, 1024) bf16 [Q | K].  vt: [512 hd][36864] bf16, col = b*192+ka.
// ctx out: stride ldc, offset colOff. S^T = mfma(K,Q): col=q, row=k.
__global__ __launch_bounds__(256)
void attn_mfma(const unsigned short* __restrict__ qk,
               const unsigned short* __restrict__ vt,
               unsigned short* __restrict__ ctx, int hbranch, int ldc, int colOff)
{
  __shared__ unsigned short P_lds[4][32 * 104];
  __shared__ float rinv[4][32];

  const int t = threadIdx.x;
  const int w = t >> 6, l = t & 63;
  const int lr = l & 15, kg = l >> 4;
  const int bid = blockIdx.x;
  const int hg = bid & 1;
  const int n = (bid >> 1) % 6;
  const int b = bid / 12;
  const int h = hg * 4 + w;
  const int kabase = (n - 1) * 32;

  bf16x8 qf[2][2];
  #pragma unroll
  for (int ct = 0; ct < 2; ++ct)
    #pragma unroll
    for (int ks = 0; ks < 2; ++ks)
      qf[ct][ks] = *(const bf16x8*)&qk[(size_t)(b * 192 + n * 32 + ct * 16 + lr) * 1024
                                       + h * 64 + ks * 32 + kg * 8];

  const f32x4 z4 = {0.f, 0.f, 0.f, 0.f};
  f32x4 sacc[6][2];
  #pragma unroll
  for (int mt = 0; mt < 6; ++mt) { sacc[mt][0] = z4; sacc[mt][1] = z4; }

  #pragma unroll
  for (int mt = 0; mt < 6; ++mt) {
    int ka = kabase + mt * 16 + lr;
    ka = ka < 0 ? 0 : (ka > 191 ? 191 : ka);
    const size_t row = hbranch ? (size_t)ka * 192 + b : (size_t)b * 192 + ka;
    #pragma unroll
    for (int ks = 0; ks < 2; ++ks) {
      bf16x8 kf = *(const bf16x8*)&qk[row * 1024 + 512 + h * 64 + ks * 32 + kg * 8];
      #pragma unroll
      for (int ct = 0; ct < 2; ++ct)
        sacc[mt][ct] = __builtin_amdgcn_mfma_f32_16x16x32_bf16(kf, qf[ct][ks],
                                                               sacc[mt][ct], 0, 0, 0);
    }
  }

  bf16x8 vf[4][3];
  #pragma unroll
  for (int dt = 0; dt < 4; ++dt)
    #pragma unroll
    for (int t2 = 0; t2 < 3; ++t2) {
      int ka0 = kabase + t2 * 32 + kg * 8;
      if (ka0 < 0 || ka0 > 184) ka0 = 0;
      vf[dt][t2] = *(const bf16x8*)&vt[(size_t)(h * 64 + dt * 16 + lr) * 36864
                                       + b * 192 + ka0];
    }

  unsigned short* Pw = &P_lds[w][0];
  #pragma unroll
  for (int ct = 0; ct < 2; ++ct) {
    const int q = ct * 16 + lr;
    float mx = -1e30f;
    #pragma unroll
    for (int mt = 0; mt < 6; ++mt)
      #pragma unroll
      for (int rr = 0; rr < 4; ++rr) {
        const int kk = mt * 16 + kg * 4 + rr;
        const int ka = kabase + kk;
        const bool valid = (kk >= q) && (kk <= q + 64) && (ka >= 0) && (ka < 192);
        const float s = valid ? sacc[mt][ct][rr] : -1e30f;
        sacc[mt][ct][rr] = s;
        mx = fmaxf(mx, s);
      }
    mx = fmaxf(mx, __shfl_xor(mx, 16));
    mx = fmaxf(mx, __shfl_xor(mx, 32));
    float sum = 0.f;
    #pragma unroll
    for (int mt = 0; mt < 6; ++mt) {
      bf16x4 pk;
      #pragma unroll
      for (int rr = 0; rr < 4; ++rr) {
        const float e = exp2f((sacc[mt][ct][rr] - mx) * 0.1803368801111137f);
        sum += e;
        pk[rr] = (__bf16)e;
      }
      *(bf16x4*)&Pw[q * 104 + mt * 16 + kg * 4] = pk;
    }
    sum += __shfl_xor(sum, 16);
    sum += __shfl_xor(sum, 32);
    if (kg == 0) rinv[w][q] = 1.0f / sum;
  }

  f32x4 oacc[2][4];
  #pragma unroll
  for (int mq = 0; mq < 2; ++mq)
    #pragma unroll
    for (int dt = 0; dt < 4; ++dt) oacc[mq][dt] = z4;

  #pragma unroll
  for (int t2 = 0; t2 < 3; ++t2)
    #pragma unroll
    for (int mq = 0; mq < 2; ++mq) {
      bf16x8 pa = *(const bf16x8*)&Pw[(mq * 16 + lr) * 104 + t2 * 32 + kg * 8];
      #pragma unroll
      for (int dt = 0; dt < 4; ++dt)
        oacc[mq][dt] = __builtin_amdgcn_mfma_f32_16x16x32_bf16(pa, vf[dt][t2],
                                                               oacc[mq][dt], 0, 0, 0);
    }

  #pragma unroll
  for (int mq = 0; mq < 2; ++mq)
    #pragma unroll
    for (int rr = 0; rr < 4; ++rr) {
      const int q = mq * 16 + kg * 4 + rr;
      const float rv = rinv[w][q];
      const size_t row = (size_t)(b * 192 + n * 32 + q) * ldc + colOff + h * 64;
      #pragma unroll
      for (int dt = 0; dt < 4; ++dt)
        ctx[row + dt * 16 + lr] = f2bf(oacc[mq][dt][rr] * rv);
    }
}

// ---------------- launch ----------------
extern "C" void kernel_launch(void* const* d_in, const int* in_sizes, int n_in,
                              void* d_out, int out_size, void* d_ws, size_t ws_size,
                              hipStream_t stream) {
  const float* x       = (const float*)d_in[0];
  const float* h_in_w  = (const float*)d_in[1];
  const float* h_in_b  = (const float*)d_in[2];
  const float* h_out_w = (const float*)d_in[3];
  const float* h_out_b = (const float*)d_in[4];
  const float* v_in_w  = (const float*)d_in[5];
  const float* v_in_b  = (const float*)d_in[6];
  const float* v_out_w = (const float*)d_in[7];
  const float* v_out_b = (const float*)d_in[8];
  const float* w1      = (const float*)d_in[9];
  const float* b1      = (const float*)d_in[10];
  const float* w2      = (const float*)d_in[11];
  const float* b2      = (const float*)d_in[12];

  // workspace layout (bytes) — total: 232,259,584
  const size_t XB   = 0;                 // xb 37,748,736
  const size_t WVB  = 37748736;
  const size_t WHB  = 39321600;
  const size_t WHOT = 40894464;
  const size_t WVOT = 41418752;
  const size_t W1B  = 41943040;
  const size_t W2B  = 42991616;
  const size_t CTX2 = 43515904;          // 75,497,472 (xt aliases here pre-attn)
  const size_t QKO  = 119013376;         // 75,497,472 (hid aliases here)
  const size_t VTO  = 194510848;         // 37,748,736 (vt [512][36864])
  const size_t NEED = 232259584;
  if (ws_size < NEED) return;

  char* ws = (char*)d_ws;
  unsigned short* xb   = (unsigned short*)(ws + XB);
  unsigned short* wvb  = (unsigned short*)(ws + WVB);
  unsigned short* whb  = (unsigned short*)(ws + WHB);
  unsigned short* whoT = (unsigned short*)(ws + WHOT);
  unsigned short* wvoT = (unsigned short*)(ws + WVOT);
  unsigned short* w1b  = (unsigned short*)(ws + W1B);
  unsigned short* w2b  = (unsigned short*)(ws + W2B);
  unsigned short* ctx2 = (unsigned short*)(ws + CTX2);
  unsigned short* xt   = (unsigned short*)(ws + CTX2); // alias: dead before attn-h writes ctx2
  unsigned short* qko  = (unsigned short*)(ws + QKO);
  unsigned short* vto  = (unsigned short*)(ws + VTO);
  unsigned short* hid  = (unsigned short*)(ws + QKO);  // alias: after attn-v
  // G + fused bias live in d_out (dead until MLP2 overwrites it). BOTH are
  // fully rewritten every call (stale-replay-state hazard, R9 lesson).
  unsigned short* G    = (unsigned short*)d_out;       // 1,048,576 B
  float*          bfz  = (float*)((char*)d_out + 1048576); // 2 KB

  // 1. converts (single kernel)
  cvt_all<<<21248, 256, 0, stream>>>(x, v_in_w, h_in_w, w1, w2, h_out_w, v_out_w,
                                     xb, xt, wvb, whb, w1b, w2b, whoT, wvoT);
  // 2. h-branch projections + G GEMMs + fused bias (one dispatch)
  proj_h<<<2368, 256, 0, stream>>>(xb, xt, whb, w1b, whoT, wvoT, vto, qko,
                                   G, bfz, h_in_b, b1, h_out_b, v_out_b, w1);
  // 3. attn-h -> ctx2 cols [0,512)  (overwrites xt alias — xt dead)
  attn_mfma<<<192 * 6 * 2, 256, 0, stream>>>(qko, vto, ctx2, 1, 1024, 0);
  // 4. v-branch projections (one dispatch; reuses vto/qko)
  proj_v<<<2304, 256, 0, stream>>>(xb, wvb, vto, qko, v_in_b);
  // 5. attn-v -> ctx2 cols [512,1024)
  attn_mfma<<<192 * 6 * 2, 256, 0, stream>>>(qko, vto, ctx2, 0, 1024, 512);
  // 6. hid = relu(ctx2 . G^T + bfz)   (out-projections folded in; 256x128)
  gemm256_bt<0,1,1><<<576, 256, 0, stream>>>(ctx2, G, hid, bfz,
                                             512, 1024, 1024, 1024, 512);
  // 7. out = hid . w2^T + b2  (fp32; 256x128 core)
  gemm256_bt<1,0,1><<<576, 256, 0, stream>>>(hid, w2b, d_out, b2,
                                             512, 512, 512, 512, 512);
}

// Round 18
// 342.905 us; speedup vs baseline: 1.0538x; 1.0538x over previous
//
#include <hip/hip_runtime.h>

typedef __bf16 bf16x8 __attribute__((ext_vector_type(8)));
typedef __bf16 bf16x4 __attribute__((ext_vector_type(4)));
typedef float f32x4 __attribute__((ext_vector_type(4)));

__device__ __forceinline__ float bf2f(unsigned short u) {
  union { unsigned int i; float f; } v; v.i = ((unsigned int)u) << 16; return v.f;
}
__device__ __forceinline__ unsigned short f2bf(float f) {
  union { float f; unsigned int i; } v; v.f = f;
  unsigned int u = v.i;
  u += 0x7fffu + ((u >> 16) & 1u);
  return (unsigned short)(u >> 16);
}

#define SB()  __builtin_amdgcn_sched_barrier(0)
#define BAR() __builtin_amdgcn_s_barrier()

// ---------------- fused convert: x (dual), flat weights, transposed who/wvo
__global__ void cvt_all(const float* __restrict__ x,
                        const float* __restrict__ wv, const float* __restrict__ wh,
                        const float* __restrict__ w1, const float* __restrict__ w2,
                        const float* __restrict__ who, const float* __restrict__ wvo,
                        unsigned short* __restrict__ xb, unsigned short* __restrict__ xt,
                        unsigned short* __restrict__ wvb, unsigned short* __restrict__ whb,
                        unsigned short* __restrict__ w1b, unsigned short* __restrict__ w2b,
                        unsigned short* __restrict__ whoT, unsigned short* __restrict__ wvoT)
{
  const int bid = blockIdx.x;
  const int t = threadIdx.x;
  if (bid < 18432) {
    const int ro = bid * 2 + (t >> 7);           // xt row = s*192+b
    const int idx = t & 127;
    const int s = ro / 192, b = ro - s * 192;
    const int ri = b * 192 + s;                  // x/xb row
    float4 v = *(const float4*)&x[(size_t)ri * 512 + idx * 4];
    ushort4 o;
    o.x = f2bf(v.x); o.y = f2bf(v.y); o.z = f2bf(v.z); o.w = f2bf(v.w);
    *(ushort4*)&xb[(size_t)ri * 512 + idx * 4] = o;
    *(ushort4*)&xt[(size_t)ro * 512 + idx * 4] = o;
  } else if (bid < 20736) {
    int q = (bid - 18432) * 256 + t;
    const float* src; unsigned short* dst;
    if (q < 196608)      { src = wv;  dst = wvb; }
    else if (q < 393216) { src = wh;  dst = whb; q -= 196608; }
    else if (q < 524288) { src = w1;  dst = w1b; q -= 393216; }
    else                 { src = w2;  dst = w2b; q -= 524288; }
    float4 v = ((const float4*)src)[q];
    ushort4 o;
    o.x = f2bf(v.x); o.y = f2bf(v.y); o.z = f2bf(v.z); o.w = f2bf(v.w);
    ((ushort4*)dst)[q] = o;
  } else {
    const int tb = bid - 20736;
    const float* src = (tb < 256) ? who : wvo;
    unsigned short* dst = (tb < 256) ? whoT : wvoT;
    const int j = (tb & 255) * 2 + (t >> 7);
    const int i0 = (t & 127) * 4;
    ushort4 o;
    o.x = f2bf(src[(size_t)(i0 + 0) * 512 + j]);
    o.y = f2bf(src[(size_t)(i0 + 1) * 512 + j]);
    o.z = f2bf(src[(size_t)(i0 + 2) * 512 + j]);
    o.w = f2bf(src[(size_t)(i0 + 3) * 512 + j]);
    *(ushort4*)&dst[(size_t)j * 512 + i0] = o;
  }
}

// ---------------- async global->LDS 16B ----------------
__device__ __forceinline__ void async16(const void* g, void* s) {
  __builtin_amdgcn_global_load_lds(
      (const __attribute__((address_space(1))) unsigned int*)g,
      (__attribute__((address_space(3))) unsigned int*)s, 16, 0, 0);
}

// ---------------- fuse_bias device body: bf = b1 + W1a.hob + W1b.vob ------
// Needs 32 blocks of 256 (o in [0,512), 16 lanes each). FULL coverage is a
// correctness requirement: bf lives in d_out, which holds stale replay data.
__device__ __forceinline__ void fuse_bias_core(int bid,
    const float* b1, const float* hob, const float* vob,
    const float* w1, float* bf)
{
  const int gid = bid * 256 + (int)threadIdx.x;
  const int o = gid >> 4, g = gid & 15;
  if (o < 512) {
    const float* row = w1 + (size_t)o * 1024;
    float s = 0.f;
    #pragma unroll 8
    for (int m = g * 32; m < g * 32 + 32; ++m) s += row[m] * hob[m];
    #pragma unroll 8
    for (int m = g * 32; m < g * 32 + 32; ++m) s += row[512 + m] * vob[m];
    s += __shfl_xor(s, 1);
    s += __shfl_xor(s, 2);
    s += __shfl_xor(s, 4);
    s += __shfl_xor(s, 8);
    if (g == 0) bf[o] = s + b1[o];
  }
}

// ======== 128x128 bf16 GEMM core, Bt = (N,K) row-major (C = A*Bt^T) =======
// FINAL config (best measured: 343.9 µs / 353.3 µs reproduction): BK=32,
// 4 waves (2x2), 3-slot LDS pipeline (48 KB -> 3 blocks/CU), prefetch
// distance 2, counted vmcnt, SINGLE barrier per K-step. Bracketed optimum:
// R13 2-slot/5-block thrashes L2; R17 256x128@2-block loses latency hiding;
// R7/R8 256^2 worse; R14 setprio neutral-negative; R15 PERMB -10 µs.
// ~512 TF effective = 88% of this tile's LDS-BW roofline.
//   head: vmcnt(4) [tile it resident, it+1 in flight] -> barrier ->
//         stage tile it+2 into slot (cur+2)%3 -> ds_read slot cur -> MFMA.
// Race audit: a wave passes barrier k+1 only after every wave finished
// iter k (slot-(cur-1) reads retired: lgkmcnt drained before pre-barrier
// MFMAs). Stage slot (cur+2)%3 = read slot of it-1, readers provably done.
// L2-locality: bijective XCD swizzle + group-major tiles (R11: FETCH
// 196->54MB). XOR-swizzle LDS (R6: conflicts=0).
// BIASROW=1: bias indexed by output ROW (V^T GEMMs, M-axis = hd channel).
template<int OUTF32, int RELU, int BIASROW, int ADDB>
__device__ __forceinline__ void gemm_core(int bid0, int nwg,
    unsigned short* As, unsigned short* Bs,
    const unsigned short* A, const unsigned short* Bt, void* Cv, const float* bias,
    int M, int N, int K, int lda, int ldb, int ldC, int colOff)
{
  const int per = nwg >> 3;
  const int lb = (bid0 & 7) * per + (bid0 >> 3);   // bijective, nwg%8==0
  const int nb = N >> 7;
  const int grp = lb / (4 * nb);
  const int r = lb - grp * 4 * nb;
  const int tm = grp * 4 + (r & 3);
  const int tn = r >> 2;

  const int t = threadIdx.x;
  const int w = t >> 6, l = t & 63;
  const int wr = w >> 1, wc = w & 1;
  const int lr = l & 15, kg = l >> 4;

  const unsigned short* Abase = A + (size_t)tm * 128 * lda;
  const unsigned short* Bbase = Bt + (size_t)tn * 128 * ldb;

  const int r0 = t >> 2;
  const int s0 = (((t & 3) ^ ((t >> 3) & 3))) * 8;
  const size_t ga0 = (size_t)r0 * lda + s0;
  const size_t ga1 = (size_t)(64 + r0) * lda + s0;
  const size_t gb0 = (size_t)r0 * ldb + s0;
  const size_t gb1 = (size_t)(64 + r0) * ldb + s0;
  const int ldsoff = w * 512;

  const f32x4 zero4 = {0.f, 0.f, 0.f, 0.f};
  f32x4 acc[4][4];
  #pragma unroll
  for (int m = 0; m < 4; ++m)
    #pragma unroll
    for (int n = 0; n < 4; ++n) acc[m][n] = zero4;

  auto stage = [&](int kt, int slot) {
    async16(Abase + ga0 + kt, &As[slot * 4096 + ldsoff]);
    async16(Abase + ga1 + kt, &As[slot * 4096 + 2048 + ldsoff]);
    async16(Bbase + gb0 + kt, &Bs[slot * 4096 + ldsoff]);
    async16(Bbase + gb1 + kt, &Bs[slot * 4096 + 2048 + ldsoff]);
  };

  const int nk = K >> 5;
  stage(0, 0);
  stage(32, 1);

  const int rsw = (kg ^ ((lr >> 1) & 3)) * 8;

  int cur = 0;
  for (int it = 0; it < nk; ++it) {
    if (it + 1 < nk) asm volatile("s_waitcnt vmcnt(4)" ::: "memory");
    else             asm volatile("s_waitcnt vmcnt(0)" ::: "memory");
    SB(); BAR(); SB();

    int st = cur + 2; if (st >= 3) st -= 3;
    if (it + 2 < nk) stage((it + 2) << 5, st);

    bf16x8 af[4], bfv[4];
    #pragma unroll
    for (int m = 0; m < 4; ++m)
      af[m] = *(const bf16x8*)&As[cur * 4096 + (wr * 64 + m * 16 + lr) * 32 + rsw];
    #pragma unroll
    for (int n = 0; n < 4; ++n)
      bfv[n] = *(const bf16x8*)&Bs[cur * 4096 + (wc * 64 + n * 16 + lr) * 32 + rsw];
    #pragma unroll
    for (int m = 0; m < 4; ++m)
      #pragma unroll
      for (int n = 0; n < 4; ++n)
        acc[m][n] = __builtin_amdgcn_mfma_f32_16x16x32_bf16(af[m], bfv[n],
                                                            acc[m][n], 0, 0, 0);
    cur = cur + 1; if (cur >= 3) cur = 0;
  }

  const int row0 = tm * 128 + wr * 64;
  const int colL0 = tn * 128 + wc * 64;

  #pragma unroll
  for (int n = 0; n < 4; ++n) {
    const int ccol = colL0 + n * 16 + lr;
    const float bvc = (ADDB && !BIASROW) ? bias[ccol] : 0.f;
    #pragma unroll
    for (int m = 0; m < 4; ++m) {
      #pragma unroll
      for (int r2 = 0; r2 < 4; ++r2) {
        const int crow = row0 + m * 16 + kg * 4 + r2;
        float v = acc[m][n][r2] + ((ADDB && BIASROW) ? bias[crow] : bvc);
        if (RELU) v = fmaxf(v, 0.f);
        if (OUTF32)
          ((float*)Cv)[(size_t)crow * ldC + colOff + ccol] = v;
        else
          ((unsigned short*)Cv)[(size_t)crow * ldC + colOff + ccol] = f2bf(v);
      }
    }
  }
}

// ---------------- standalone GEMM kernel (MLP1 / MLP2) --------------------
template<int OUTF32, int RELU, int BIASROW, int ADDB>
__global__ __launch_bounds__(256, 3)
void gemm_bt(const unsigned short* __restrict__ A,
             const unsigned short* __restrict__ Bt,
             void* __restrict__ Cv, const float* __restrict__ bias,
             int M, int N, int K, int lda, int ldb, int ldC, int colOff)
{
  __shared__ unsigned short smem[3 * 4096 * 2];   // 48 KB: 3 slots x (A,B)
  gemm_core<OUTF32, RELU, BIASROW, ADDB>((int)blockIdx.x, (int)gridDim.x,
                                         smem, smem + 12288,
                                         A, Bt, Cv, bias, M, N, K, lda, ldb, ldC, colOff);
}

// ---------------- merged h-branch projection dispatch ---------------------
// [0,1152): VT-h  C=vt[512][36864] = Wv_h . xt^T   (bias by row)
// [1152,3456): QK-h (36864x1024)
// [3456,3472): G1 = W1a.who^T; [3472,3488): G2 = W1b.wvo^T;
// [3488,3520): fused bias (32 blocks — FULL 512-entry coverage).
// Section offsets multiples of 8 (XCD id preserved per section).
__global__ __launch_bounds__(256, 3)
void proj_h(const unsigned short* __restrict__ xb, const unsigned short* __restrict__ xt,
            const unsigned short* __restrict__ whb,
            const unsigned short* __restrict__ w1b,
            const unsigned short* __restrict__ whoT, const unsigned short* __restrict__ wvoT,
            unsigned short* __restrict__ vto, unsigned short* __restrict__ qko,
            unsigned short* __restrict__ G, float* __restrict__ bfz,
            const float* __restrict__ h_in_b,
            const float* __restrict__ b1, const float* __restrict__ hob,
            const float* __restrict__ vob, const float* __restrict__ w1f)
{
  __shared__ unsigned short smem[3 * 4096 * 2];
  const int bid = (int)blockIdx.x;
  if (bid < 1152)
    gemm_core<0,0,1,1>(bid, 1152, smem, smem + 12288, whb + 1024 * 512, xt, vto,
                       h_in_b + 1024, 512, 36864, 512, 512, 512, 36864, 0);
  else if (bid < 3456)
    gemm_core<0,0,0,1>(bid - 1152, 2304, smem, smem + 12288, xb, whb, qko,
                       h_in_b, 36864, 1024, 512, 512, 512, 1024, 0);
  else if (bid < 3472)
    gemm_core<0,0,0,0>(bid - 3456, 16, smem, smem + 12288, w1b, whoT, G,
                       bfz, 512, 512, 512, 1024, 512, 1024, 0);
  else if (bid < 3488)
    gemm_core<0,0,0,0>(bid - 3472, 16, smem, smem + 12288, w1b + 512, wvoT, G,
                       bfz, 512, 512, 512, 1024, 512, 1024, 512);
  else
    fuse_bias_core(bid - 3488, b1, hob, vob, w1f, bfz);
}

// ---------------- merged v-branch projection dispatch ---------------------
// [0,1152): VT-v  C=vt[512][36864] = Wv_v . xb^T   (bias by row)
// [1152,3456): QK-v
__global__ __launch_bounds__(256, 3)
void proj_v(const unsigned short* __restrict__ xb,
            const unsigned short* __restrict__ wvb,
            unsigned short* __restrict__ vto, unsigned short* __restrict__ qko,
            const float* __restrict__ v_in_b)
{
  __shared__ unsigned short smem[3 * 4096 * 2];
  const int bid = (int)blockIdx.x;
  if (bid < 1152)
    gemm_core<0,0,1,1>(bid, 1152, smem, smem + 12288, wvb + 1024 * 512, xb, vto,
                       v_in_b + 1024, 512, 36864, 512, 512, 512, 36864, 0);
  else
    gemm_core<0,0,0,1>(bid - 1152, 2304, smem, smem + 12288, xb, wvb, qko,
                       v_in_b, 36864, 1024, 512, 512, 512, 1024, 0);
}

// ---------------- MFMA sliding-window attention ---------------------------
// Block = (b, n, head-group of 4). Wave w handles head hg*4+w independently.
// qk: (36864, 1024) bf16 [Q | K].  vt: [512 hd][36864] bf16, col = b*192+ka
// (identical indexing for both branches). ctx out: stride ldc, offset colOff.
// S^T = mfma(K,Q): col=q, row=k.
__global__ __launch_bounds__(256)
void attn_mfma(const unsigned short* __restrict__ qk,
               const unsigned short* __restrict__ vt,
               unsigned short* __restrict__ ctx, int hbranch, int ldc, int colOff)
{
  __shared__ unsigned short P_lds[4][32 * 104];
  __shared__ float rinv[4][32];

  const int t = threadIdx.x;
  const int w = t >> 6, l = t & 63;
  const int lr = l & 15, kg = l >> 4;
  const int bid = blockIdx.x;
  const int hg = bid & 1;
  const int n = (bid >> 1) % 6;
  const int b = bid / 12;
  const int h = hg * 4 + w;
  const int kabase = (n - 1) * 32;

  bf16x8 qf[2][2];
  #pragma unroll
  for (int ct = 0; ct < 2; ++ct)
    #pragma unroll
    for (int ks = 0; ks < 2; ++ks)
      qf[ct][ks] = *(const bf16x8*)&qk[(size_t)(b * 192 + n * 32 + ct * 16 + lr) * 1024
                                       + h * 64 + ks * 32 + kg * 8];

  const f32x4 z4 = {0.f, 0.f, 0.f, 0.f};
  f32x4 sacc[6][2];
  #pragma unroll
  for (int mt = 0; mt < 6; ++mt) { sacc[mt][0] = z4; sacc[mt][1] = z4; }

  #pragma unroll
  for (int mt = 0; mt < 6; ++mt) {
    int ka = kabase + mt * 16 + lr;
    ka = ka < 0 ? 0 : (ka > 191 ? 191 : ka);
    const size_t row = hbranch ? (size_t)ka * 192 + b : (size_t)b * 192 + ka;
    #pragma unroll
    for (int ks = 0; ks < 2; ++ks) {
      bf16x8 kf = *(const bf16x8*)&qk[row * 1024 + 512 + h * 64 + ks * 32 + kg * 8];
      #pragma unroll
      for (int ct = 0; ct < 2; ++ct)
        sacc[mt][ct] = __builtin_amdgcn_mfma_f32_16x16x32_bf16(kf, qf[ct][ks],
                                                               sacc[mt][ct], 0, 0, 0);
    }
  }

  bf16x8 vf[4][3];
  #pragma unroll
  for (int dt = 0; dt < 4; ++dt)
    #pragma unroll
    for (int t2 = 0; t2 < 3; ++t2) {
      int ka0 = kabase + t2 * 32 + kg * 8;
      if (ka0 < 0 || ka0 > 184) ka0 = 0;
      vf[dt][t2] = *(const bf16x8*)&vt[(size_t)(h * 64 + dt * 16 + lr) * 36864
                                       + b * 192 + ka0];
    }

  unsigned short* Pw = &P_lds[w][0];
  #pragma unroll
  for (int ct = 0; ct < 2; ++ct) {
    const int q = ct * 16 + lr;
    float mx = -1e30f;
    #pragma unroll
    for (int mt = 0; mt < 6; ++mt)
      #pragma unroll
      for (int rr = 0; rr < 4; ++rr) {
        const int kk = mt * 16 + kg * 4 + rr;
        const int ka = kabase + kk;
        const bool valid = (kk >= q) && (kk <= q + 64) && (ka >= 0) && (ka < 192);
        const float s = valid ? sacc[mt][ct][rr] : -1e30f;
        sacc[mt][ct][rr] = s;
        mx = fmaxf(mx, s);
      }
    mx = fmaxf(mx, __shfl_xor(mx, 16));
    mx = fmaxf(mx, __shfl_xor(mx, 32));
    float sum = 0.f;
    #pragma unroll
    for (int mt = 0; mt < 6; ++mt) {
      bf16x4 pk;
      #pragma unroll
      for (int rr = 0; rr < 4; ++rr) {
        const float e = exp2f((sacc[mt][ct][rr] - mx) * 0.1803368801111137f);
        sum += e;
        pk[rr] = (__bf16)e;
      }
      *(bf16x4*)&Pw[q * 104 + mt * 16 + kg * 4] = pk;
    }
    sum += __shfl_xor(sum, 16);
    sum += __shfl_xor(sum, 32);
    if (kg == 0) rinv[w][q] = 1.0f / sum;
  }

  f32x4 oacc[2][4];
  #pragma unroll
  for (int mq = 0; mq < 2; ++mq)
    #pragma unroll
    for (int dt = 0; dt < 4; ++dt) oacc[mq][dt] = z4;

  #pragma unroll
  for (int t2 = 0; t2 < 3; ++t2)
    #pragma unroll
    for (int mq = 0; mq < 2; ++mq) {
      bf16x8 pa = *(const bf16x8*)&Pw[(mq * 16 + lr) * 104 + t2 * 32 + kg * 8];
      #pragma unroll
      for (int dt = 0; dt < 4; ++dt)
        oacc[mq][dt] = __builtin_amdgcn_mfma_f32_16x16x32_bf16(pa, vf[dt][t2],
                                                               oacc[mq][dt], 0, 0, 0);
    }

  #pragma unroll
  for (int mq = 0; mq < 2; ++mq)
    #pragma unroll
    for (int rr = 0; rr < 4; ++rr) {
      const int q = mq * 16 + kg * 4 + rr;
      const float rv = rinv[w][q];
      const size_t row = (size_t)(b * 192 + n * 32 + q) * ldc + colOff + h * 64;
      #pragma unroll
      for (int dt = 0; dt < 4; ++dt)
        ctx[row + dt * 16 + lr] = f2bf(oacc[mq][dt][rr] * rv);
    }
}

// ---------------- launch ----------------
extern "C" void kernel_launch(void* const* d_in, const int* in_sizes, int n_in,
                              void* d_out, int out_size, void* d_ws, size_t ws_size,
                              hipStream_t stream) {
  const float* x       = (const float*)d_in[0];
  const float* h_in_w  = (const float*)d_in[1];
  const float* h_in_b  = (const float*)d_in[2];
  const float* h_out_w = (const float*)d_in[3];
  const float* h_out_b = (const float*)d_in[4];
  const float* v_in_w  = (const float*)d_in[5];
  const float* v_in_b  = (const float*)d_in[6];
  const float* v_out_w = (const float*)d_in[7];
  const float* v_out_b = (const float*)d_in[8];
  const float* w1      = (const float*)d_in[9];
  const float* b1      = (const float*)d_in[10];
  const float* w2      = (const float*)d_in[11];
  const float* b2      = (const float*)d_in[12];

  // workspace layout (bytes) — total: 232,259,584
  const size_t XB   = 0;                 // xb 37,748,736
  const size_t WVB  = 37748736;
  const size_t WHB  = 39321600;
  const size_t WHOT = 40894464;
  const size_t WVOT = 41418752;
  const size_t W1B  = 41943040;
  const size_t W2B  = 42991616;
  const size_t CTX2 = 43515904;          // 75,497,472 (xt aliases here pre-attn)
  const size_t QKO  = 119013376;         // 75,497,472 (hid aliases here)
  const size_t VTO  = 194510848;         // 37,748,736 (vt [512][36864])
  const size_t NEED = 232259584;
  if (ws_size < NEED) return;

  char* ws = (char*)d_ws;
  unsigned short* xb   = (unsigned short*)(ws + XB);
  unsigned short* wvb  = (unsigned short*)(ws + WVB);
  unsigned short* whb  = (unsigned short*)(ws + WHB);
  unsigned short* whoT = (unsigned short*)(ws + WHOT);
  unsigned short* wvoT = (unsigned short*)(ws + WVOT);
  unsigned short* w1b  = (unsigned short*)(ws + W1B);
  unsigned short* w2b  = (unsigned short*)(ws + W2B);
  unsigned short* ctx2 = (unsigned short*)(ws + CTX2);
  unsigned short* xt   = (unsigned short*)(ws + CTX2); // alias: dead before attn-h writes ctx2
  unsigned short* qko  = (unsigned short*)(ws + QKO);
  unsigned short* vto  = (unsigned short*)(ws + VTO);
  unsigned short* hid  = (unsigned short*)(ws + QKO);  // alias: after attn-v
  // G + fused bias live in d_out (dead until MLP2 overwrites it). BOTH are
  // fully rewritten every call (stale-replay-state hazard, R9 lesson).
  unsigned short* G    = (unsigned short*)d_out;       // 1,048,576 B
  float*          bfz  = (float*)((char*)d_out + 1048576); // 2 KB

  // 1. converts (single kernel)
  cvt_all<<<21248, 256, 0, stream>>>(x, v_in_w, h_in_w, w1, w2, h_out_w, v_out_w,
                                     xb, xt, wvb, whb, w1b, w2b, whoT, wvoT);
  // 2. h-branch projections + G GEMMs + fused bias (one dispatch)
  proj_h<<<3520, 256, 0, stream>>>(xb, xt, whb, w1b, whoT, wvoT, vto, qko,
                                   G, bfz, h_in_b, b1, h_out_b, v_out_b, w1);
  // 3. attn-h -> ctx2 cols [0,512)  (overwrites xt alias — xt dead)
  attn_mfma<<<192 * 6 * 2, 256, 0, stream>>>(qko, vto, ctx2, 1, 1024, 0);
  // 4. v-branch projections (one dispatch; reuses vto/qko)
  proj_v<<<3456, 256, 0, stream>>>(xb, wvb, vto, qko, v_in_b);
  // 5. attn-v -> ctx2 cols [512,1024)
  attn_mfma<<<192 * 6 * 2, 256, 0, stream>>>(qko, vto, ctx2, 0, 1024, 512);
  // 6. hid = relu(ctx2 . G^T + bfz)   (out-projections folded in)
  gemm_bt<0,1,0,1><<<288 * 4, 256, 0, stream>>>(ctx2, G, hid, bfz,
                                                36864, 512, 1024, 1024, 1024, 512, 0);
  // 7. out = hid . w2^T + b2  (fp32; overwrites G region after MLP1 done)
  gemm_bt<1,0,0,1><<<288 * 4, 256, 0, stream>>>(hid, w2b, d_out, b2,
                                                36864, 512, 512, 512, 512, 512, 0);
}